// Round 1
// baseline (6291.024 us; speedup 1.0000x reference)
//
#include <hip/hip_runtime.h>
#include <math.h>

#define NBATCH 4096

// ---------------------------------------------------------------------------
// LAPACK scalar helpers (single precision, faithful transcriptions)
// ---------------------------------------------------------------------------

__device__ __forceinline__ float wave64_sum(float v){
  #pragma unroll
  for(int off=32; off; off>>=1) v += __shfl_xor(v, off, 64);
  return v;
}

// slartg, LAPACK >= 3.10 convention (well-scaled path)
__device__ __forceinline__ void slartgf(float f, float g, float* cs, float* sn, float* r){
  if (g == 0.0f){ *cs = 1.0f; *sn = 0.0f; *r = f; }
  else if (f == 0.0f){ *cs = 0.0f; *sn = copysignf(1.0f, g); *r = fabsf(g); }
  else {
    float d = sqrtf(f*f + g*g);
    *cs = fabsf(f)/d;
    float rr = copysignf(d, f);
    *r = rr;
    *sn = g/rr;
  }
}

__device__ __forceinline__ void slas2f(float f, float g, float hh, float* ssmin, float* ssmax){
  float fa=fabsf(f), ga=fabsf(g), ha=fabsf(hh);
  float fhmn=fminf(fa,ha), fhmx=fmaxf(fa,ha);
  if (fhmn == 0.0f){
    *ssmin = 0.0f;
    if (fhmx == 0.0f) *ssmax = ga;
    else { float mx=fmaxf(fhmx,ga), mn=fminf(fhmx,ga); float q=mn/mx; *ssmax = mx*sqrtf(1.0f+q*q); }
  } else {
    if (ga < fhmx){
      float as_=1.0f+fhmn/fhmx;
      float at_=(fhmx-fhmn)/fhmx;
      float au_=(ga/fhmx); au_=au_*au_;
      float c_=2.0f/(sqrtf(as_*as_+au_)+sqrtf(at_*at_+au_));
      *ssmin=fhmn*c_;
      *ssmax=fhmx/c_;
    } else {
      float au_=fhmx/ga;
      if (au_==0.0f){ *ssmin=(fhmn*fhmx)/ga; *ssmax=ga; }
      else {
        float as_=1.0f+fhmn/fhmx;
        float at_=(fhmx-fhmn)/fhmx;
        float t1=as_*au_, t2=at_*au_;
        float c_=1.0f/(sqrtf(1.0f+t1*t1)+sqrtf(1.0f+t2*t2));
        float sm=(fhmn*c_)*au_;
        *ssmin=sm+sm;
        *ssmax=ga/(c_+c_);
      }
    }
  }
}

__device__ __forceinline__ void slasv2f(float f, float g, float hh,
    float* ssmin, float* ssmax, float* snr, float* csr, float* snl, float* csl){
  const float EPS2 = 5.9604644775390625e-08f; // slamch('E') single
  float ft=f, fa=fabsf(f), ht=hh, ha=fabsf(hh);
  int pmax=1;
  bool swap_=(ha>fa);
  if (swap_){ pmax=3; float tmp=ft; ft=ht; ht=tmp; tmp=fa; fa=ha; ha=tmp; }
  float gt=g, ga=fabsf(g);
  float clt=0.f, crt=0.f, slt=0.f, srt=0.f;
  if (ga==0.0f){ *ssmin=ha; *ssmax=fa; clt=1.f; crt=1.f; slt=0.f; srt=0.f; }
  else {
    bool gasmal=true;
    if (ga>fa){
      pmax=2;
      if ((fa/ga) < EPS2){
        gasmal=false;
        *ssmax=ga;
        if (ha>1.0f) *ssmin=fa/(ga/ha); else *ssmin=(fa/ga)*ha;
        clt=1.f; slt=ht/gt; srt=1.f; crt=ft/gt;
      }
    }
    if (gasmal){
      float d_=fa-ha;
      float l_;
      if (d_==fa) l_=1.0f; else l_=d_/fa;
      float m_=gt/ft;
      float t_=2.0f-l_;
      float mm=m_*m_, tt=t_*t_;
      float s_=sqrtf(tt+mm);
      float r_;
      if (l_==0.0f) r_=fabsf(m_); else r_=sqrtf(l_*l_+mm);
      float a_=0.5f*(s_+r_);
      *ssmin=ha/a_;
      *ssmax=fa*a_;
      if (mm==0.0f){
        if (l_==0.0f) t_=copysignf(2.0f,ft)*copysignf(1.0f,gt);
        else t_=gt/copysignf(d_,ft)+m_/t_;
      } else {
        t_=(m_/(s_+t_)+m_/(r_+l_))*(1.0f+a_);
      }
      l_=sqrtf(t_*t_+4.0f);
      crt=2.0f/l_;
      srt=t_/l_;
      clt=(crt+srt*m_)/a_;
      slt=(ht/ft)*srt/a_;
    }
  }
  if (swap_){ *csl=srt; *snl=crt; *csr=slt; *snr=clt; }
  else { *csl=clt; *snl=slt; *csr=crt; *snr=srt; }
  float tsign=0.f;
  if (pmax==1) tsign=copysignf(1.f,*csr)*copysignf(1.f,*csl)*copysignf(1.f,f);
  if (pmax==2) tsign=copysignf(1.f,*snr)*copysignf(1.f,*csl)*copysignf(1.f,g);
  if (pmax==3) tsign=copysignf(1.f,*snr)*copysignf(1.f,*snl)*copysignf(1.f,hh);
  *ssmax=copysignf(*ssmax,tsign);
  *ssmin=copysignf(*ssmin,tsign*copysignf(1.f,f)*copysignf(1.f,hh));
}

// ---------------------------------------------------------------------------
// Kernel 1: per-batch init — sgesdd path-9t emulation + wd init
// grid 4096, block 64 (1 wave)
// ---------------------------------------------------------------------------
__global__ __launch_bounds__(64) void init_kernel(
    const float* __restrict__ h,
    const float* __restrict__ wd_init,
    float* __restrict__ out_wa,   // b0 slice region: [4096][128][16]
    float* __restrict__ out_wd)   // [8][4096][16][16]
{
  const int batch = blockIdx.x;
  const int lane  = threadIdx.x;
  if (batch >= NBATCH) return;

  __shared__ float A[16][128];
  __shared__ float Qc[128][16];
  __shared__ float Lm[16][16];
  __shared__ float VTs[16][16];
  __shared__ float Wtop[16][16];
  __shared__ float tauL[16], tq[16], tp[16];
  __shared__ float dB[16], eB[16];
  volatile __shared__ float dsh[17];
  volatile __shared__ float esh[17];

  // ---- A = mean over b of h ----
  for(int e0=lane; e0<2048; e0+=64){
    int nn=e0>>7, mmi=e0&127;
    float s=0.f;
    #pragma unroll
    for(int i=0;i<8;i++) s += h[((size_t)(i*NBATCH+batch))*2048 + nn*128 + mmi];
    A[nn][mmi]=s*0.125f;
  }
  __syncthreads();

  // ---- sgelq2: LQ factorization, reflectors left in A rows, taus in tauL ----
  for(int i=0;i<16;i++){
    float part=0.f;
    for(int j=i+1+lane;j<128;j+=64){ float v=A[i][j]; part+=v*v; }
    float xn2=wave64_sum(part);
    float alpha=A[i][i];
    float tau,beta,scal;
    if (xn2==0.0f){ tau=0.f; beta=alpha; scal=0.f; }
    else {
      beta=-copysignf(sqrtf(alpha*alpha+xn2), alpha);
      tau=(beta-alpha)/beta;
      scal=1.0f/(alpha-beta);
    }
    if (tau!=0.0f){
      for(int j=i+1+lane;j<128;j+=64) A[i][j]*=scal;
    }
    if (lane==0){ A[i][i]=beta; tauL[i]=tau; }
    __syncthreads();
    if (tau!=0.0f){
      for(int r=i+1;r<16;r++){
        float p=0.f;
        for(int j=i+1+lane;j<128;j+=64) p += A[r][j]*A[i][j];
        float w=wave64_sum(p) + A[r][i];
        float tw=tau*w;
        for(int j=i+1+lane;j<128;j+=64) A[r][j]-=tw*A[i][j];
        if (lane==0) A[r][i]-=tw;
      }
    }
    __syncthreads();
  }

  // ---- Q columns 0..15 : Q = H(16)...H(1), col_j = product applied to e_j ----
  for(int j=0;j<16;j++){
    float c0 = (lane==j)?1.0f:0.0f;
    float c1 = 0.0f;
    for(int i=0;i<16;i++){
      float tau=tauL[i];
      float p=0.f;
      if (lane>i) p += A[i][lane]*c0;
      else if (lane==i) p += c0;
      p += A[i][64+lane]*c1;
      float w=wave64_sum(p);
      if (tau!=0.0f){
        float tw=tau*w;
        if (lane==i) c0 -= tw;
        else if (lane>i) c0 -= tw*A[i][lane];
        c1 -= tw*A[i][64+lane];
      }
    }
    Qc[lane][j]=c0;
    Qc[64+lane][j]=c1;
  }
  __syncthreads();

  // ---- L (lower triangular 16x16), strict upper zero ----
  for(int e0=lane;e0<256;e0+=64){ int r=e0>>4,c=e0&15; Lm[r][c]=(c<=r)?A[r][c]:0.0f; }
  __syncthreads();

  // ---- sgebd2 on L (m=n=16, upper bidiagonal) ----
  for(int i=0;i<16;i++){
    // column reflector H(i)
    float alpha=Lm[i][i];
    float xn2=0.f;
    for(int r=i+1;r<16;r++){ float v=Lm[r][i]; xn2+=v*v; }
    float tauqi,beta,scal;
    if (xn2==0.0f){ tauqi=0.f; beta=alpha; scal=0.f; }
    else { beta=-copysignf(sqrtf(alpha*alpha+xn2),alpha); tauqi=(beta-alpha)/beta; scal=1.0f/(alpha-beta); }
    __syncthreads();
    if (lane==0){
      tq[i]=tauqi; dB[i]=beta;
      if (tauqi!=0.0f) for(int r=i+1;r<16;r++) Lm[r][i]*=scal;
    }
    __syncthreads();
    if (tauqi!=0.0f && lane>i && lane<16){
      int c=lane;
      float w=Lm[i][c];
      for(int r=i+1;r<16;r++) w += Lm[r][i]*Lm[r][c];
      float tw=tauqi*w;
      Lm[i][c]-=tw;
      for(int r=i+1;r<16;r++) Lm[r][c]-=tw*Lm[r][i];
    }
    __syncthreads();
    if (i<15){
      float alph2=Lm[i][i+1];
      float yn2=0.f;
      for(int c=i+2;c<16;c++){ float v=Lm[i][c]; yn2+=v*v; }
      float taupi,beta2,scal2;
      if (yn2==0.0f){ taupi=0.f; beta2=alph2; scal2=0.f; }
      else { beta2=-copysignf(sqrtf(alph2*alph2+yn2),alph2); taupi=(beta2-alph2)/beta2; scal2=1.0f/(alph2-beta2); }
      __syncthreads();
      if (lane==0){
        tp[i]=taupi; eB[i]=beta2;
        if (taupi!=0.0f) for(int c=i+2;c<16;c++) Lm[i][c]*=scal2;
      }
      __syncthreads();
      if (taupi!=0.0f && lane>i && lane<16){
        int r=lane;
        float w=Lm[r][i+1];
        for(int c=i+2;c<16;c++) w += Lm[i][c]*Lm[r][c];
        float tw=taupi*w;
        Lm[r][i+1]-=tw;
        for(int c=i+2;c<16;c++) Lm[r][c]-=tw*Lm[i][c];
      }
      __syncthreads();
    } else {
      if (lane==0) tp[i]=0.0f;
      __syncthreads();
    }
  }

  // ---- sbdsqr ('U', n=16, NCVT=16, NRU=0) ----
  if (lane==0){
    for(int k=1;k<=16;k++) dsh[k]=dB[k-1];
    for(int k=1;k<=15;k++) esh[k]=eB[k-1];
  }
  if (lane<16){
    for(int r=0;r<16;r++) VTs[r][lane]=(r==lane)?1.0f:0.0f;
  }
  __syncthreads();
  {
    const float EPSB = 5.9604644775390625e-08f;
    const float UNFL = 1.1754943508222875e-38f;
    const float tolb = 10.0f*EPSB;   // tolmul = max(10, min(100, eps^-1/8)) = 10
    float sminoa;
    {
      sminoa=fabsf(dsh[1]);
      if (sminoa!=0.0f){
        float mu=sminoa;
        for(int k=2;k<=16;k++){
          mu=fabsf(dsh[k])*(mu/(mu+fabsf(esh[k-1])));
          sminoa=fminf(sminoa,mu);
          if (sminoa==0.0f) break;
        }
      }
      sminoa*=0.25f; // / sqrt(16)
    }
    float thresh=fmaxf(tolb*sminoa, 6.0f*256.0f*UNFL);
    int maxitdivn=6*16, iterdivn=0, iter_=-1;
    int oldll=-1, oldm=-1, idir=0;
    int mq=16;
    float sminl=0.0f;
    int guard=0;
    while (guard++ < 4000){
      if (mq<=1) break;
      if (iter_>=16){ iter_-=16; iterdivn++; if (iterdivn>=maxitdivn) break; }
      float smax=fabsf(dsh[mq]);
      int ll=0; bool split=false;
      for(int lll=1;lll<=mq-1;lll++){
        int l2=mq-lll;
        float abss=fabsf(dsh[l2]);
        float abse=fabsf(esh[l2]);
        if (abse<=thresh){ ll=l2; split=true; break; }
        smax=fmaxf(smax,fmaxf(abss,abse));
      }
      if (split){
        if (lane==0) esh[ll]=0.0f;
        if (ll==mq-1){ mq=mq-1; continue; }
        ll=ll+1;
      } else ll=1;
      if (ll==mq-1){
        float sigmn,sigmx,sinr,cosr,sinl_,cosl_;
        slasv2f(dsh[mq-1],esh[mq-1],dsh[mq],&sigmn,&sigmx,&sinr,&cosr,&sinl_,&cosl_);
        if (lane==0){ dsh[mq-1]=sigmx; esh[mq-1]=0.0f; dsh[mq]=sigmn; }
        if (lane<16){
          float x0=VTs[mq-2][lane], y0=VTs[mq-1][lane];
          VTs[mq-2][lane]=cosr*x0+sinr*y0;
          VTs[mq-1][lane]=cosr*y0-sinr*x0;
        }
        mq-=2;
        continue;
      }
      if (ll>oldm || mq<oldll)
        idir=(fabsf(dsh[ll])>=fabsf(dsh[mq]))?1:2;
      bool conv=false;
      if (idir==1){
        if (fabsf(esh[mq-1])<=tolb*fabsf(dsh[mq])){ if(lane==0) esh[mq-1]=0.0f; conv=true; }
        if (!conv){
          float mu=fabsf(dsh[ll]); sminl=mu;
          for(int lll=ll;lll<=mq-1;lll++){
            if (fabsf(esh[lll])<=tolb*mu){ if(lane==0) esh[lll]=0.0f; conv=true; break; }
            mu=fabsf(dsh[lll+1])*(mu/(mu+fabsf(esh[lll])));
            sminl=fminf(sminl,mu);
          }
        }
      } else {
        if (fabsf(esh[ll])<=tolb*fabsf(dsh[ll])){ if(lane==0) esh[ll]=0.0f; conv=true; }
        if (!conv){
          float mu=fabsf(dsh[mq]); sminl=mu;
          for(int lll=mq-1;lll>=ll;lll--){
            if (fabsf(esh[lll])<=tolb*mu){ if(lane==0) esh[lll]=0.0f; conv=true; break; }
            mu=fabsf(dsh[lll])*(mu/(mu+fabsf(esh[lll])));
            sminl=fminf(sminl,mu);
          }
        }
      }
      if (conv) continue;
      oldll=ll; oldm=mq;
      float shift=0.0f, rdum;
      if (!( 16.0f*tolb*(sminl/smax) <= fmaxf(EPSB, 0.01f*tolb) )){
        float sll;
        if (idir==1){ sll=fabsf(dsh[ll]); slas2f(dsh[mq-1],esh[mq-1],dsh[mq],&shift,&rdum); }
        else        { sll=fabsf(dsh[mq]); slas2f(dsh[ll],esh[ll],dsh[ll+1],&shift,&rdum); }
        if (sll>0.0f){ float q=shift/sll; if (q*q<EPSB) shift=0.0f; }
      }
      iter_ += mq-ll;
      if (shift==0.0f){
        if (idir==1){
          float cs=1.0f, oldcs=1.0f, sn=0.0f, oldsn=0.0f, r1, r2;
          for(int i=ll;i<=mq-1;i++){
            slartgf(dsh[i]*cs, esh[i], &cs, &sn, &r1);
            if (i>ll){ if(lane==0) esh[i-1]=oldsn*r1; }
            slartgf(oldcs*r1, dsh[i+1]*sn, &oldcs, &oldsn, &r2);
            if (lane==0) dsh[i]=r2;
            if (lane<16){
              float lo=VTs[i-1][lane], hi=VTs[i][lane];
              VTs[i][lane]  =cs*hi-sn*lo;
              VTs[i-1][lane]=sn*hi+cs*lo;
            }
          }
          float hval=dsh[mq]*cs;
          float nd=hval*oldcs, ne=hval*oldsn;
          if (lane==0){ dsh[mq]=nd; esh[mq-1]=(fabsf(ne)<=thresh)?0.0f:ne; }
        } else {
          float cs=1.0f, oldcs=1.0f, sn=0.0f, oldsn=0.0f, r1, r2;
          for(int i=mq;i>=ll+1;i--){
            slartgf(dsh[i]*cs, esh[i-1], &cs, &sn, &r1);
            if (i<mq){ if(lane==0) esh[i]=oldsn*r1; }
            slartgf(oldcs*r1, dsh[i-1]*sn, &oldcs, &oldsn, &r2);
            if (lane==0) dsh[i]=r2;
            if (lane<16){
              float lo=VTs[i-2][lane], hi=VTs[i-1][lane];
              float c_=oldcs, s_=-oldsn;
              VTs[i-1][lane]=c_*hi-s_*lo;
              VTs[i-2][lane]=s_*hi+c_*lo;
            }
          }
          float hval=dsh[ll]*cs;
          float nd=hval*oldcs, ne=hval*oldsn;
          if (lane==0){ dsh[ll]=nd; esh[ll]=(fabsf(ne)<=thresh)?0.0f:ne; }
        }
      } else {
        if (idir==1){
          float dll=dsh[ll];
          float f=(fabsf(dll)-shift)*(copysignf(1.0f,dll)+shift/dll);
          float g=esh[ll];
          float cosr,sinr,cosl_,sinl_,r1;
          for(int i=ll;i<=mq-1;i++){
            slartgf(f,g,&cosr,&sinr,&r1);
            if (i>ll){ if(lane==0) esh[i-1]=r1; }
            float di=dsh[i], ei=esh[i], dip=dsh[i+1];
            f=cosr*di+sinr*ei;
            float ei1=cosr*ei-sinr*di;
            g=sinr*dip;
            float dip1=cosr*dip;
            slartgf(f,g,&cosl_,&sinl_,&r1);
            if (lane==0) dsh[i]=r1;
            f=cosl_*ei1+sinl_*dip1;
            float dip2=cosl_*dip1-sinl_*ei1;
            float eip2=0.0f;
            if (i<mq-1){
              float eip=esh[i+1];
              g=sinl_*eip;
              eip2=cosl_*eip;
            }
            if (lane==0){
              esh[i]=ei1;
              dsh[i+1]=dip2;
              if (i<mq-1) esh[i+1]=eip2;
            }
            if (lane<16){
              float lo=VTs[i-1][lane], hi=VTs[i][lane];
              VTs[i][lane]  =cosr*hi-sinr*lo;
              VTs[i-1][lane]=sinr*hi+cosr*lo;
            }
          }
          if (lane==0) esh[mq-1]=(fabsf(f)<=thresh)?0.0f:f;
        } else {
          float dm=dsh[mq];
          float f=(fabsf(dm)-shift)*(copysignf(1.0f,dm)+shift/dm);
          float g=esh[mq-1];
          float cosr,sinr,cosl_,sinl_,r1;
          for(int i=mq;i>=ll+1;i--){
            slartgf(f,g,&cosr,&sinr,&r1);
            if (i<mq){ if(lane==0) esh[i]=r1; }
            float di=dsh[i], eim=esh[i-1], dim=dsh[i-1];
            f=cosr*di+sinr*eim;
            float eim1=cosr*eim-sinr*di;
            g=sinr*dim;
            float dim1=cosr*dim;
            slartgf(f,g,&cosl_,&sinl_,&r1);
            if (lane==0) dsh[i]=r1;
            f=cosl_*eim1+sinl_*dim1;
            float dim2=cosl_*dim1-sinl_*eim1;
            float eim3=0.0f;
            if (i>ll+1){
              float e2=esh[i-2];
              g=sinl_*e2;
              eim3=cosl_*e2;
            }
            if (lane==0){
              esh[i-1]=eim1;
              dsh[i-1]=dim2;
              if (i>ll+1) esh[i-2]=eim3;
            }
            if (lane<16){
              float lo=VTs[i-2][lane], hi=VTs[i-1][lane];
              float c_=cosl_, s_=-sinl_;
              VTs[i-1][lane]=c_*hi-s_*lo;
              VTs[i-2][lane]=s_*hi+c_*lo;
            }
          }
          if (lane==0) esh[ll]=(fabsf(f)<=thresh)?0.0f:f;
        }
      }
    }
    // make singular values positive (flip VT rows)
    for(int k=1;k<=16;k++){
      float dv=dsh[k];
      if (dv<0.0f){
        if (lane==0) dsh[k]=-dv;
        if (lane<16) VTs[k-1][lane]=-VTs[k-1][lane];
      }
    }
    // sort into decreasing order
    for(int i=1;i<=15;i++){
      int isub=1; float smn=dsh[1];
      for(int j=2;j<=17-i;j++){ float dj=dsh[j]; if (dj<=smn){ isub=j; smn=dj; } }
      if (isub!=17-i){
        if (lane==0){ dsh[isub]=dsh[17-i]; dsh[17-i]=smn; }
        if (lane<16){ float tv=VTs[isub-1][lane]; VTs[isub-1][lane]=VTs[16-i][lane]; VTs[16-i][lane]=tv; }
      }
    }
  }
  __syncthreads();

  // ---- apply P^T (gebrd right reflectors): VT_L = VT_b * G(14)...G(0) ----
  for(int i=14;i>=0;i--){
    float tau=tp[i];
    if (tau!=0.0f && lane<16){
      int r=lane;
      float w=VTs[r][i+1];
      for(int c=i+2;c<16;c++) w += VTs[r][c]*Lm[i][c];
      float tw=tau*w;
      VTs[r][i+1]-=tw;
      for(int c=i+2;c<16;c++) VTs[r][c]-=tw*Lm[i][c];
    }
  }
  __syncthreads();

  // ---- Wtop = VT_L * Q[0:16, 0:16]; wa = [Wtop ; Q[16:128, 0:16]] ----
  for(int e0=lane;e0<256;e0+=64){
    int r=e0>>4, j=e0&15;
    float s=0.f;
    #pragma unroll
    for(int c=0;c<16;c++) s += VTs[r][c]*Qc[c][j];
    Wtop[r][j]=s;
  }
  __syncthreads();
  for(int e0=lane;e0<2048;e0+=64){
    int r=e0>>4, j=e0&15;
    out_wa[(size_t)batch*2048 + e0] = (r<16)?Wtop[r][j]:Qc[r][j];
  }

  // ---- wd init: scale = sqrt(128 / sum_i ||wa @ wd_init_i||_F^2) ----
  float part=0.f;
  for(int i=0;i<8;i++){
    const float* wdi = wd_init + ((size_t)(i*NBATCH+batch))*256;
    for(int e=lane;e<256;e+=64) ((float*)Lm)[e]=wdi[e];
    __syncthreads();
    for(int e0=lane;e0<2048;e0+=64){
      int r=e0>>4, j=e0&15;
      float s=0.f;
      #pragma unroll
      for(int c=0;c<16;c++){
        float wav=(r<16)?Wtop[r][c]:Qc[r][c];
        s += wav*((float*)Lm)[c*16+j];
      }
      part += s*s;
    }
    __syncthreads();
  }
  float fro2=wave64_sum(part);
  float scal2=sqrtf(128.0f/fro2);
  for(int i=0;i<8;i++){
    const float* wdi = wd_init + ((size_t)(i*NBATCH+batch))*256;
    float* wdo = out_wd + ((size_t)(i*NBATCH+batch))*256;
    for(int e=lane;e<256;e+=64) wdo[e]=scal2*wdi[e];
  }
}

// ---------------------------------------------------------------------------
// Kernel 2: per-batch 5-iteration projected gradient ascent
// grid 4096, block 256
// ---------------------------------------------------------------------------
__global__ __launch_bounds__(256) void iter_kernel(
    const float* __restrict__ h,
    const float* __restrict__ hyp,
    float* __restrict__ out_obj,
    float* __restrict__ out_wa,
    float* __restrict__ out_wd)
{
  const int batch = blockIdx.x;
  const int t = threadIdx.x;
  if (batch >= NBATCH) return;

  __shared__ float Wf[2048];                  // wa [128][16]
  __shared__ __align__(16) float Hs[2048];    // staged h_i [16][128]
  __shared__ float Uf[2048];                  // u_i = h_i@wa, [8][16][16]
  __shared__ float Wdf[2048];                 // wd [8][16][16]
  __shared__ float Wdtf[2048];                // wd_t
  __shared__ float Cvf[2048];                 // cov -> inv [8][16][16]
  __shared__ float F2f[2048];                 // grad_wa accum [128][16]
  __shared__ float Gmf[256];                  // Gram wa^T wa
  __shared__ float T1f[256];
  __shared__ float T2f[256];
  __shared__ float T3f[256];
  __shared__ float redbuf[4];
  __shared__ float bcv[2];
  __shared__ float hyps[45];
  __shared__ float logdets[8];

  const int r16 = t>>4, c16 = t&15;

  {
    const float* src = out_wa + (size_t)batch*2048;
    for(int e=t;e<2048;e+=256) Wf[e]=src[e];
    for(int i=0;i<8;i++){
      const float* s2 = out_wd + ((size_t)(i*NBATCH+batch))*256;
      Wdf[i*256+t]=s2[t];
    }
    if (t<45) hyps[t]=hyp[t];
  }
  __syncthreads();

  auto stage_h = [&](int i){
    const float4* h4 = reinterpret_cast<const float4*>(h + ((size_t)(i*NBATCH+batch))*2048);
    float4* s4 = reinterpret_cast<float4*>(Hs);
    s4[t]=h4[t];
    s4[t+256]=h4[t+256];
  };
  auto compute_u = [&](int i){
    const float4* Hs4 = reinterpret_cast<const float4*>(Hs);
    float s=0.f;
    #pragma unroll
    for(int m4=0;m4<32;m4++){
      float4 hv=Hs4[r16*32+m4];
      s += hv.x*Wf[(m4*4+0)*16+c16];
      s += hv.y*Wf[(m4*4+1)*16+c16];
      s += hv.z*Wf[(m4*4+2)*16+c16];
      s += hv.w*Wf[(m4*4+3)*16+c16];
    }
    Uf[i*256+t]=s;
  };
  auto block_red = [&](float v)->float{
    #pragma unroll
    for(int off=32;off;off>>=1) v += __shfl_xor(v, off, 64);
    if ((t&63)==0) redbuf[t>>6]=v;
    __syncthreads();
    if (t==0) bcv[0]=redbuf[0]+redbuf[1]+redbuf[2]+redbuf[3];
    __syncthreads();
    return bcv[0];
  };
  // batched 8x GJ inverse (no pivoting, SPD) in Cvf, returns logdets[]
  auto batched_gj = [&](){
    int ii=t>>5, ss=t&31;
    float logacc=0.f;
    for(int k=0;k<16;k++){
      float piv=Cvf[ii*256+k*16+k];
      float rk8[8],ck8[8],cur8[8];
      #pragma unroll
      for(int q=0;q<8;q++){
        int e=ss*8+q; int rr=e>>4, cc=e&15;
        rk8[q]=Cvf[ii*256+k*16+cc];
        ck8[q]=Cvf[ii*256+rr*16+k];
        cur8[q]=Cvf[ii*256+e];
      }
      __syncthreads();
      float pinv=1.0f/piv;
      if (ss==0) logacc += logf(piv);
      #pragma unroll
      for(int q=0;q<8;q++){
        int e=ss*8+q; int rr=e>>4, cc=e&15;
        float v;
        if (rr==k) v=(cc==k)?pinv:rk8[q]*pinv;
        else if (cc==k) v=-ck8[q]*pinv;
        else v=cur8[q]-ck8[q]*pinv*rk8[q];
        Cvf[ii*256+e]=v;
      }
      __syncthreads();
    }
    if (ss==0) logdets[ii]=logacc;
    __syncthreads();
  };
  auto build_cov_all = [&](){
    for(int i=0;i<8;i++){
      float s=0.f;
      #pragma unroll
      for(int k=0;k<16;k++) s += Uf[i*256+r16*16+k]*Wdf[i*256+k*16+c16];
      T1f[t]=s;
      __syncthreads();
      float cv=(r16==c16)?1.0f:0.0f;
      #pragma unroll
      for(int k=0;k<16;k++) cv += T1f[r16*16+k]*T1f[c16*16+k];
      Cvf[i*256+t]=cv;
      __syncthreads();
    }
  };

  // ---- initial U (wa = wa0) ----
  for(int i=0;i<8;i++){ stage_h(i); __syncthreads(); compute_u(i); __syncthreads(); }

  for(int x=0;x<5;x++){
    // ================= phase 1: grad_wa (+ obj of iter x-1) =================
    build_cov_all();
    batched_gj();
    if (x>0 && t==0){
      float s=0.f;
      for(int i=0;i<8;i++) s+=logdets[i];
      out_obj[batch*5+(x-1)]=s*0.125f;
    }
    for(int e=t;e<2048;e+=256) F2f[e]=0.f;
    __syncthreads();
    for(int i=0;i<8;i++){
      // T1 = inv^T @ u_i
      float s=0.f;
      #pragma unroll
      for(int k=0;k<16;k++) s += Cvf[i*256+k*16+r16]*Uf[i*256+k*16+c16];
      T1f[t]=s; __syncthreads();
      // T2 = T1 @ wd_i
      s=0.f;
      #pragma unroll
      for(int k=0;k<16;k++) s += T1f[r16*16+k]*Wdf[i*256+k*16+c16];
      T2f[t]=s; __syncthreads();
      // T3 = T2 @ wd_i^T
      s=0.f;
      #pragma unroll
      for(int k=0;k<16;k++) s += T2f[r16*16+k]*Wdf[i*256+c16*16+k];
      T3f[t]=s; __syncthreads();
      stage_h(i); __syncthreads();
      // F2 += h_i^T @ T3
      {
        int mm=t>>1, l0=(t&1)*8;
        float a0=0,a1=0,a2=0,a3=0,a4=0,a5=0,a6=0,a7=0;
        #pragma unroll
        for(int nn=0;nn<16;nn++){
          float hv=Hs[nn*128+mm];
          const float* T3r=&T3f[nn*16+l0];
          a0+=hv*T3r[0]; a1+=hv*T3r[1]; a2+=hv*T3r[2]; a3+=hv*T3r[3];
          a4+=hv*T3r[4]; a5+=hv*T3r[5]; a6+=hv*T3r[6]; a7+=hv*T3r[7];
        }
        float* F2r=&F2f[mm*16+l0];
        F2r[0]+=a0; F2r[1]+=a1; F2r[2]+=a2; F2r[3]+=a3;
        F2r[4]+=a4; F2r[5]+=a5; F2r[6]+=a6; F2r[7]+=a7;
      }
      __syncthreads();
    }
    // ================= phase 2: wa update + renorm =================
    {
      float hyp0=hyps[x*9]*0.125f;
      for(int e=t;e<2048;e+=256) Wf[e] += hyp0*F2f[e];
      __syncthreads();
      float s=0.f;
      #pragma unroll 8
      for(int mmi=0;mmi<128;mmi++) s += Wf[mmi*16+r16]*Wf[mmi*16+c16];
      Gmf[t]=s;
      __syncthreads();
      float part=0.f;
      for(int j=0;j<8;j++){
        float gw=0.f;
        #pragma unroll
        for(int k=0;k<16;k++) gw += Gmf[r16*16+k]*Wdf[j*256+k*16+c16];
        part += gw*Wdf[j*256+t];
      }
      float fro2=block_red(part);
      float scal=sqrtf(128.0f/fro2);
      for(int e=t;e<2048;e+=256) Wf[e]*=scal;
      Gmf[t]*=scal*scal;
      __syncthreads();
    }
    // ================= phase 3: recompute U with new wa =================
    for(int i=0;i<8;i++){ stage_h(i); __syncthreads(); compute_u(i); __syncthreads(); }
    // ================= inner loop: sequential wd updates =================
    for(int e=t;e<2048;e+=256) Wdtf[e]=Wdf[e];
    __syncthreads();
    for(int i=0;i<8;i++){
      // t_i = u_i @ wd_i
      float s=0.f;
      #pragma unroll
      for(int k=0;k<16;k++) s += Uf[i*256+r16*16+k]*Wdf[i*256+k*16+c16];
      T1f[t]=s; __syncthreads();
      // cov
      float cv=(r16==c16)?1.0f:0.0f;
      #pragma unroll
      for(int k=0;k<16;k++) cv += T1f[r16*16+k]*T1f[c16*16+k];
      T2f[t]=cv; __syncthreads();
      // GJ invert T2f (single 16x16)
      for(int k=0;k<16;k++){
        float piv=T2f[k*16+k];
        float rk=T2f[k*16+c16];
        float ck=T2f[r16*16+k];
        float cur=T2f[t];
        __syncthreads();
        float pinv=1.0f/piv;
        float v;
        if (r16==k) v=(c16==k)?pinv:rk*pinv;
        else if (c16==k) v=-ck*pinv;
        else v=cur-ck*pinv*rk;
        T2f[t]=v;
        __syncthreads();
      }
      // M1 = u^T @ inv^T
      s=0.f;
      #pragma unroll
      for(int k=0;k<16;k++) s += Uf[i*256+k*16+r16]*T2f[c16*16+k];
      T1f[t]=s; __syncthreads();
      // M2 = M1 @ u
      s=0.f;
      #pragma unroll
      for(int k=0;k<16;k++) s += T1f[r16*16+k]*Uf[i*256+k*16+c16];
      T3f[t]=s; __syncthreads();
      // g = M2 @ wd_i / 8 ; wd_t[i] = wd[i] + hyp*g
      {
        float g=0.f;
        #pragma unroll
        for(int k=0;k<16;k++) g += T3f[r16*16+k]*Wdf[i*256+k*16+c16];
        g*=0.125f;
        Wdtf[i*256+t]=Wdf[i*256+t]+hyps[x*9+i+1]*g;
      }
      __syncthreads();
      // renorm: wd = sqrt(128 / sum_j tr(wdt_j^T G wdt_j)) * wdt
      {
        float part=0.f;
        for(int j=0;j<8;j++){
          float gw=0.f;
          #pragma unroll
          for(int k=0;k<16;k++) gw += Gmf[r16*16+k]*Wdtf[j*256+k*16+c16];
          part += gw*Wdtf[j*256+t];
        }
        float fro2=block_red(part);
        float scal=sqrtf(128.0f/fro2);
        for(int e=t;e<2048;e+=256) Wdf[e]=scal*Wdtf[e];
      }
      __syncthreads();
    }
  }
  // ---- final obj[4] ----
  build_cov_all();
  batched_gj();
  if (t==0){
    float s=0.f;
    for(int i=0;i<8;i++) s+=logdets[i];
    out_obj[batch*5+4]=s*0.125f;
  }
  __syncthreads();
  // ---- outputs ----
  for(int i=0;i<8;i++){
    float* dst = out_wa + ((size_t)(i*NBATCH+batch))*2048;
    for(int e=t;e<2048;e+=256) dst[e]=Wf[e];
  }
  for(int i=0;i<8;i++){
    float* dst = out_wd + ((size_t)(i*NBATCH+batch))*256;
    dst[t]=Wdf[i*256+t];
  }
}

// ---------------------------------------------------------------------------
extern "C" void kernel_launch(void* const* d_in, const int* in_sizes, int n_in,
                              void* d_out, int out_size, void* d_ws, size_t ws_size,
                              hipStream_t stream)
{
  (void)in_sizes; (void)n_in; (void)d_ws; (void)ws_size; (void)out_size;
  const float* h   = (const float*)d_in[0];
  const float* wdi = (const float*)d_in[1];
  const float* hyp = (const float*)d_in[2];
  float* out = (float*)d_out;
  float* out_obj = out;                                   // 4096*5
  float* out_wa  = out + (size_t)NBATCH*5;                // 8*4096*128*16
  float* out_wd  = out_wa + (size_t)8*NBATCH*128*16;      // 8*4096*16*16

  init_kernel<<<NBATCH, 64, 0, stream>>>(h, wdi, out_wa, out_wd);
  iter_kernel<<<NBATCH, 256, 0, stream>>>(h, hyp, out_obj, out_wa, out_wd);
}